// Round 15
// baseline (188.023 us; speedup 1.0000x reference)
//
#include <hip/hip_runtime.h>

#define NB     8
#define TNEW   1024
#define TCACHE 3072
#define TTOT   4096
#define EMB    512
#define HD     64

typedef __bf16 bf16x8 __attribute__((ext_vector_type(8)));
typedef __bf16 bf16x4 __attribute__((ext_vector_type(4)));
typedef float  f32x4  __attribute__((ext_vector_type(4)));

#define MFMA(a,b,c) __builtin_amdgcn_mfma_f32_16x16x32_bf16((a),(b),(c),0,0,0)

#define GLOAD_LDS16(g, l) \
    __builtin_amdgcn_global_load_lds((const __attribute__((address_space(1))) void*)(g), \
                                     (__attribute__((address_space(3))) void*)(l), 16, 0, 0)

// log2-domain scale: 1/sqrt(64) * 1/ln(2)
#define QSCALE 0.180336880f

// ---------- ws layout (bytes) ----------
#define WS_WT   0          // 3*64*512*2 = 196608   WT[m][d][c] bf16
#define WS_KBF  196608     // 8*4096*64*2 = 4194304
#define WS_VTB  4390912    // 8*64*4096*2 = 4194304 (per batch: Vt[d][s], sigma-permuted per 64-tile)
#define WS_OP   8585216    // 8*8192*64*2 = 8388608 (bf16 [split][row][d])
#define WS_ML   16973824   // 8*8192*2*4  = 524288  (f32 [split][row][{m,l}], log2 domain)
#define WS_CNT  17498112   // 64*4 = 256 (qblock completion counters; zeroed by prep)

// vtb column permutation within each 64-aligned tile: column c' holds V col
// sigma(c'); sigma^-1(s) = ((s>>2)&3)*8 + ((s>>4)&1)*4 + (s&3).

// ---------------- k1: fused prep ----------------
__global__ __launch_bounds__(256) void prep(const float* __restrict__ ck,
                                            const float* __restrict__ cv,
                                            const float* __restrict__ Wq,
                                            const float* __restrict__ Wk,
                                            const float* __restrict__ Wv,
                                            float* __restrict__ kout,
                                            float* __restrict__ vout,
                                            __bf16* __restrict__ kb,
                                            __bf16* __restrict__ vtb,
                                            __bf16* __restrict__ wt,
                                            int* __restrict__ cnt) {
    __shared__ __bf16 vl[64][72];              // 9216 B, shared by V and W branches
    const int blk = blockIdx.x;
    const int tid = threadIdx.x;
    if (blk == 1152 && tid < 64) cnt[tid] = 0; // reset combine counters (runs before attn)
    if (blk < 768) {
#pragma unroll
        for (int it = 0; it < 2; ++it) {
            const int i = blk * 256 + tid + it * 196608;
            const int b = i / 49152;
            const int f = i - b * 49152;
            const int s = f >> 4, d = (f & 15) * 4;
            const float4 kd = ((const float4*)ck)[i];
            ((float4*)(kout + (size_t)b * TTOT * HD))[f] = kd;
            bf16x4 k4;
            k4[0] = (__bf16)kd.x; k4[1] = (__bf16)kd.y;
            k4[2] = (__bf16)kd.z; k4[3] = (__bf16)kd.w;
            *(bf16x4*)(kb + (size_t)b * TTOT * HD + s * HD + d) = k4;
        }
    } else if (blk < 1152) {
        const int tb = blk - 768;
        const int b = tb / 48, si = tb - (tb / 48) * 48;
        const int sbase = si * 64;
        const float4* src = (const float4*)(cv + ((size_t)b * TCACHE + sbase) * HD);
        float4* dstf = (float4*)(vout + ((size_t)b * TTOT + sbase) * HD);
#pragma unroll
        for (int k = 0; k < 4; ++k) {
            const int f = tid + 256 * k;
            const int s = f >> 4, d4 = (f & 15) * 4;
            const float4 v = src[f];
            dstf[f] = v;
            bf16x4 t;
            t[0] = (__bf16)v.x; t[1] = (__bf16)v.y;
            t[2] = (__bf16)v.z; t[3] = (__bf16)v.w;
            *(bf16x4*)&vl[s][d4] = t;
        }
        __syncthreads();
        const int d = tid >> 2, sc = tid & 3;
        // sigma-permuted write
        __bf16* vt = vtb + ((size_t)b * HD + d) * TTOT + sbase + (sc >> 1) * 32 + (sc & 1) * 4;
#pragma unroll
        for (int t4 = 0; t4 < 4; ++t4) {
            bf16x4 o;
#pragma unroll
            for (int c = 0; c < 4; ++c) o[c] = vl[sc * 16 + t4 * 4 + c][d];
            *(bf16x4*)(vt + t4 * 8) = o;
        }
    } else {
        const int tb = blk - 1152;                 // 0..23
        const int m = tb >> 3;
        const int ct = (tb & 7) * 64;
        const float* W = (m == 0) ? Wq : (m == 1) ? Wk : Wv;
        const float4* src = (const float4*)(W + (size_t)ct * HD);
#pragma unroll
        for (int k = 0; k < 4; ++k) {
            const int f = tid + 256 * k;
            const int c = f >> 4, d4 = (f & 15) * 4;
            const float4 v = src[f];
            bf16x4 t;
            t[0] = (__bf16)v.x; t[1] = (__bf16)v.y;
            t[2] = (__bf16)v.z; t[3] = (__bf16)v.w;
            *(bf16x4*)&vl[c][d4] = t;
        }
        __syncthreads();
        const int d = tid >> 2, sc = tid & 3;
        bf16x8 o0, o1;
#pragma unroll
        for (int i = 0; i < 8; ++i) {
            o0[i] = vl[sc * 16 + i][d];
            o1[i] = vl[sc * 16 + 8 + i][d];
        }
        __bf16* wr = wt + (size_t)m * HD * EMB + (size_t)d * EMB + ct + sc * 16;
        *(bf16x8*)wr = o0;
        *(bf16x8*)(wr + 8) = o1;
    }
}

// ---------------- k2: MFMA projections (2 waves/block, 32 rows, grid 256) ----------------
__global__ __launch_bounds__(128) void proj_mfma(const float* __restrict__ x,
                                                 const __bf16* __restrict__ wt,
                                                 __bf16* __restrict__ qb,
                                                 float* __restrict__ kout,
                                                 float* __restrict__ vout,
                                                 __bf16* __restrict__ kb,
                                                 __bf16* __restrict__ vtb) {
    __shared__ __bf16 xs[32][520];                 // 33 KB
    __shared__ __bf16 vls[2][64][24];              // 6 KB
    const int tid = threadIdx.x;
    const int w = tid >> 6, lane = tid & 63;
    const int lo = lane & 15, hi = lane >> 4;
    const int r0 = blockIdx.x * 32 + w * 16;
    const int b = r0 >> 10;
    const int t0r = r0 & (TNEW - 1);

    {   // stage 32x512 f32 -> bf16 LDS (coalesced)
        const float4* xg = (const float4*)(x + (size_t)blockIdx.x * 32 * EMB);
#pragma unroll
        for (int k = 0; k < 32; ++k) {
            const int f = tid + 128 * k;           // 0..4095
            const int row = f >> 7, col4 = (f & 127) * 4;
            const float4 v = xg[f];
            bf16x4 t;
            t[0] = (__bf16)v.x; t[1] = (__bf16)v.y;
            t[2] = (__bf16)v.z; t[3] = (__bf16)v.w;
            *(bf16x4*)&xs[row][col4] = t;
        }
    }
    __syncthreads();

    for (int m = 0; m < 3; ++m) {
        const __bf16* wm = wt + (size_t)m * HD * EMB;
        f32x4 acc[4];
#pragma unroll
        for (int n = 0; n < 4; ++n) acc[n] = (f32x4){0.f, 0.f, 0.f, 0.f};
#pragma unroll
        for (int c = 0; c < 16; ++c) {
            const bf16x8 ax = *(const bf16x8*)&xs[w * 16 + lo][c * 32 + hi * 8];
#pragma unroll
            for (int n = 0; n < 4; ++n) {
                const bf16x8 bw = *(const bf16x8*)(wm + (size_t)(n * 16 + lo) * EMB + c * 32 + hi * 8);
                acc[n] = MFMA(ax, bw, acc[n]);
            }
        }
#pragma unroll
        for (int n = 0; n < 4; ++n) {
#pragma unroll
            for (int rr = 0; rr < 4; ++rr) {
                const int grow = r0 + hi * 4 + rr;
                const int t = grow & (TNEW - 1);
                const int d = n * 16 + lo;
                const float val = acc[n][rr];
                if (m == 0) {
                    qb[(size_t)grow * HD + d] = (__bf16)(val * QSCALE);
                } else if (m == 1) {
                    const size_t kv = ((size_t)b * TTOT + TCACHE + t) * HD + d;
                    kout[kv] = val;
                    kb[kv] = (__bf16)val;
                } else {
                    const size_t kv = ((size_t)b * TTOT + TCACHE + t) * HD + d;
                    vout[kv] = val;
                    vls[w][d][hi * 4 + rr] = (__bf16)val;
                }
            }
        }
    }
    __syncthreads();
    // sigma-permuted vt write: wave covers 16 cols at TCACHE + t0r (16-aligned)
    {
        const int tb4 = TCACHE + (t0r & ~63);
        const int m4 = (t0r >> 4) & 3;
        __bf16* vt = vtb + ((size_t)b * HD + lane) * TTOT + tb4 + (m4 >> 1) * 32 + (m4 & 1) * 4;
#pragma unroll
        for (int t4 = 0; t4 < 4; ++t4) {
            bf16x4 o;
#pragma unroll
            for (int c = 0; c < 4; ++c) o[c] = vls[w][lane][t4 * 4 + c];
            *(bf16x4*)(vt + t4 * 8) = o;
        }
    }
}

// ---------------- k3: flash attention + folded combine (last-block-done) ----------------
// grid 512 = 8 batches x 8 qblocks(128 rows) x 8 cyclic splits; 8 waves x 16 rows.
// All 512 blocks co-resident (2/CU); Q read in prologue => combine's out-writes
// (aliasing qb) cannot race any Q read.
#define QB 128
#define NSPLIT 8
__global__ __launch_bounds__(512, 4) void attn_mfma(const __bf16* __restrict__ qb,
                                                    const __bf16* __restrict__ kb,
                                                    const __bf16* __restrict__ vtb,
                                                    __bf16* __restrict__ Opart,
                                                    float* __restrict__ mlpart,
                                                    float* __restrict__ out,
                                                    int* __restrict__ cnt) {
    __shared__ __align__(16) __bf16 Kt[3][64 * 64];      // 24 KB
    __shared__ __align__(16) __bf16 Vts[3][64 * 64];     // 24 KB  (48 KB -> grid-limited 2 blk/CU)
    __shared__ int sflag;

    const int tid = threadIdx.x;
    const int wv = tid >> 6, lane = tid & 63;
    const int lo = lane & 15, hi = lane >> 4;

    const int bid = blockIdx.x;
    const int b = bid & 7;                 // XCD-major
    const int idx = bid >> 3;              // 0..63
    const int split = idx & 7;
    const int qloc = idx >> 3;             // 0..7
    const int t0 = qloc * QB;
    const int row0 = b * TNEW + t0;

    const int ntiles = (TCACHE + t0 + QB) >> 6;          // 50 + 2*qloc
    const int count = (ntiles - split + 7) >> 3;         // 6..7, uniform

    const __bf16* Kb = kb + (size_t)b * TTOT * HD;
    const __bf16* Vb = vtb + (size_t)b * HD * TTOT;

    const int r_sub = lane >> 3;                       // 0..7
    const int row_st = wv * 8 + r_sub;
    const int c_st = ((lane & 7) * 16) ^ (r_sub << 4);

#define STAGE(s, bi) do { \
        const char* gk_ = (const char*)Kb + (size_t)((s) + row_st) * 128 + c_st; \
        const char* gv_ = (const char*)Vb + ((size_t)row_st * TTOT + (s)) * 2 + c_st; \
        GLOAD_LDS16(gk_, Kt[bi] + row_st * 64); \
        GLOAD_LDS16(gv_, Vts[bi] + row_st * 64); \
    } while (0)

    const int t0w = t0 + wv * 16;
    const __bf16* Qw = qb + (size_t)(row0 + wv * 16) * HD;
    const bf16x8 aq0 = *(const bf16x8*)(Qw + (size_t)lo * HD + hi * 8);
    const bf16x8 aq1 = *(const bf16x8*)(Qw + (size_t)lo * HD + 32 + hi * 8);

    f32x4 o[4];
    float mg = -1e30f, lg = 0.f;
#pragma unroll
    for (int n = 0; n < 4; ++n) o[n] = (f32x4){0.f, 0.f, 0.f, 0.f};

    // ---- prologue: 2-deep prefetch ----
    STAGE(split * 64, 0);
    if (count > 1) {
        STAGE(split * 64 + 512, 1);
        asm volatile("s_waitcnt vmcnt(2)" ::: "memory");
    } else {
        asm volatile("s_waitcnt vmcnt(0)" ::: "memory");
    }
    __builtin_amdgcn_s_barrier();
    __builtin_amdgcn_sched_barrier(0);

    const int sw = (lo & 7) << 3;   // element-level read swizzle

    int s0 = split * 64;
    int buf = 0;
    for (int it = 0; it < count; ++it, s0 += NSPLIT * 64) {
        const __bf16* Kl = Kt[buf];
        const __bf16* Vl = Vts[buf];

        // ---- QK^T (swapped): per-kg K loads to bound register pressure ----
        const f32x4 z = (f32x4){0.f, 0.f, 0.f, 0.f};
        f32x4 sc[4];
#pragma unroll
        for (int kg = 0; kg < 4; ++kg) {
            const int kr = (kg * 16 + lo) * 64;
            const bf16x8 bk0 = *(const bf16x8*)(Kl + kr + ((hi * 8) ^ sw));
            const bf16x8 bk1 = *(const bf16x8*)(Kl + kr + ((32 + hi * 8) ^ sw));
            sc[kg] = MFMA(bk0, aq0, z);
            sc[kg] = MFMA(bk1, aq1, sc[kg]);
        }

        if (s0 + 63 > TCACHE + t0w) {
            const int lim = TCACHE + t0w + lo;   // per-lane q-row limit
#pragma unroll
            for (int kg = 0; kg < 4; ++kg)
#pragma unroll
                for (int rr = 0; rr < 4; ++rr)
                    if (s0 + kg * 16 + hi * 4 + rr > lim) sc[kg][rr] = -1e30f;
        }

        // ---- row max: 15 in-lane + 2 shuffles ----
        f32x4 mx = sc[0];
        mx = (f32x4){fmaxf(mx[0], sc[1][0]), fmaxf(mx[1], sc[1][1]),
                     fmaxf(mx[2], sc[1][2]), fmaxf(mx[3], sc[1][3])};
        mx = (f32x4){fmaxf(mx[0], sc[2][0]), fmaxf(mx[1], sc[2][1]),
                     fmaxf(mx[2], sc[2][2]), fmaxf(mx[3], sc[2][3])};
        mx = (f32x4){fmaxf(mx[0], sc[3][0]), fmaxf(mx[1], sc[3][1]),
                     fmaxf(mx[2], sc[3][2]), fmaxf(mx[3], sc[3][3])};
        float mt = fmaxf(fmaxf(mx[0], mx[1]), fmaxf(mx[2], mx[3]));
        mt = fmaxf(mt, __shfl_xor(mt, 16));
        mt = fmaxf(mt, __shfl_xor(mt, 32));

        if (__any(mt > mg + 8.0f)) {          // defer-max rescale (rare)
            const float mn = fmaxf(mg, mt);
            const float corr = exp2f(mg - mn);
            lg *= corr;
            mg = mn;
            float cb[4];
#pragma unroll
            for (int rr = 0; rr < 4; ++rr) cb[rr] = __shfl(corr, hi * 4 + rr);
#pragma unroll
            for (int n = 0; n < 4; ++n)
#pragma unroll
                for (int rr = 0; rr < 4; ++rr) o[n][rr] *= cb[rr];
        }

        // ---- exp + sum; P stays in registers (lane-local A-fragments) ----
        float e[4][4];
        float ps = 0.f;
#pragma unroll
        for (int kg = 0; kg < 4; ++kg) {
#pragma unroll
            for (int rr = 0; rr < 4; ++rr) {
                e[kg][rr] = exp2f(sc[kg][rr] - mg);
                ps += e[kg][rr];
            }
        }
        ps += __shfl_xor(ps, 16);
        ps += __shfl_xor(ps, 32);
        lg += ps;

        bf16x8 ap0, ap1;
#pragma unroll
        for (int rr = 0; rr < 4; ++rr) {
            ap0[rr]     = (__bf16)e[0][rr];
            ap0[4 + rr] = (__bf16)e[1][rr];
            ap1[rr]     = (__bf16)e[2][rr];
            ap1[4 + rr] = (__bf16)e[3][rr];
        }

        // ---- PV in two halves (sigma-permuted vtb aligns V k-rows) ----
#pragma unroll
        for (int n = 0; n < 4; ++n) {
            const int vr = (n * 16 + lo) * 64;
            const bf16x8 bv0 = *(const bf16x8*)(Vl + vr + ((hi * 8) ^ sw));
            o[n] = MFMA(ap0, bv0, o[n]);
        }
#pragma unroll
        for (int n = 0; n < 4; ++n) {
            const int vr = (n * 16 + lo) * 64;
            const bf16x8 bv1 = *(const bf16x8*)(Vl + vr + ((32 + hi * 8) ^ sw));
            o[n] = MFMA(ap1, bv1, o[n]);
        }

        // ---- prefetch tile it+2 into buf consumed at it-1 ----
        if (it + 2 < count) {
            int nb = buf + 2; if (nb >= 3) nb -= 3;
            STAGE(s0 + 2 * NSPLIT * 64, nb);
        }
        if (it + 1 < count) {
            if (it + 2 < count) { asm volatile("s_waitcnt vmcnt(2)" ::: "memory"); }
            else                { asm volatile("s_waitcnt vmcnt(0)" ::: "memory"); }
            __builtin_amdgcn_s_barrier();
            __builtin_amdgcn_sched_barrier(0);
        }
        buf = (buf == 2) ? 0 : buf + 1;
    }
#undef STAGE

    // ---- write partials ----
    __bf16* Ow = Opart + ((size_t)split * (NB * TNEW) + row0 + wv * 16) * HD;
#pragma unroll
    for (int n = 0; n < 4; ++n)
#pragma unroll
        for (int rr = 0; rr < 4; ++rr)
            Ow[(size_t)(hi * 4 + rr) * HD + n * 16 + lo] = (__bf16)o[n][rr];
    if (hi == 0) {
        float* mlw = mlpart + ((size_t)split * (NB * TNEW) + row0 + wv * 16) * 2;
        mlw[lo * 2]     = mg;
        mlw[lo * 2 + 1] = lg;
    }

    // ---- last-block-done combine for this qblock ----
    __threadfence();                        // release this block's partials (device scope)
    __syncthreads();                        // all waves' stores+fences done
    if (tid == 0) sflag = atomicAdd(&cnt[b * 8 + qloc], 1);
    __syncthreads();
    if (sflag == NSPLIT - 1) {
        __threadfence();                    // acquire other blocks' partials
        for (int ee = tid; ee < QB * HD; ee += 512) {
            const int r = ee >> 6, d = ee & 63;
            const int row = row0 + r;
            float ms[NSPLIT], ls[NSPLIT];
            float mf = -1e30f;
#pragma unroll
            for (int s = 0; s < NSPLIT; ++s) {
                const float2 v2 = *(const float2*)&mlpart[((size_t)s * (NB * TNEW) + row) * 2];
                ms[s] = v2.x; ls[s] = v2.y;
                mf = fmaxf(mf, v2.x);
            }
            float lf = 0.f, acc = 0.f;
#pragma unroll
            for (int s = 0; s < NSPLIT; ++s) {
                const float f = exp2f(ms[s] - mf);
                lf += ls[s] * f;
                acc += (float)Opart[((size_t)s * (NB * TNEW) + row) * HD + d] * f;
            }
            out[(size_t)row * HD + d] = acc / lf;
        }
    }
}

extern "C" void kernel_launch(void* const* d_in, const int* in_sizes, int n_in,
                              void* d_out, int out_size, void* d_ws, size_t ws_size,
                              hipStream_t stream) {
    (void)in_sizes; (void)n_in; (void)out_size; (void)ws_size;
    const float* x  = (const float*)d_in[0];
    const float* ck = (const float*)d_in[2];
    const float* cv = (const float*)d_in[3];
    const float* Wq = (const float*)d_in[4];
    const float* Wk = (const float*)d_in[5];
    const float* Wv = (const float*)d_in[6];

    float* out  = (float*)d_out;
    float* kout = out + (size_t)NB * TNEW * HD;
    float* vout = kout + (size_t)NB * TTOT * HD;

    char* ws = (char*)d_ws;
    __bf16* wt  = (__bf16*)(ws + WS_WT);
    __bf16* kbf = (__bf16*)(ws + WS_KBF);
    __bf16* vtb = (__bf16*)(ws + WS_VTB);
    __bf16* Op  = (__bf16*)(ws + WS_OP);
    float*  ml  = (float*)(ws + WS_ML);
    int*    cnt = (int*)(ws + WS_CNT);
    __bf16* qb  = (__bf16*)d_out;

    prep<<<dim3(1176), dim3(256), 0, stream>>>(ck, cv, Wq, Wk, Wv, kout, vout, kbf, vtb, wt, cnt);
    proj_mfma<<<dim3(256), dim3(128), 0, stream>>>(x, wt, qb, kout, vout, kbf, vtb);
    attn_mfma<<<dim3(512), dim3(512), 0, stream>>>(qb, kbf, vtb, Op, ml, out, cnt);
}

// Round 16
// 50.023 us; speedup vs baseline: 3.7587x; 3.7587x over previous
//
#include <hip/hip_runtime.h>

#define NB     8
#define TNEW   1024
#define TCACHE 3072
#define TTOT   4096
#define EMB    512
#define HD     64

typedef __bf16 bf16x8 __attribute__((ext_vector_type(8)));
typedef __bf16 bf16x4 __attribute__((ext_vector_type(4)));
typedef float  f32x4  __attribute__((ext_vector_type(4)));

#define MFMA(a,b,c) __builtin_amdgcn_mfma_f32_16x16x32_bf16((a),(b),(c),0,0,0)

#define GLOAD_LDS16(g, l) \
    __builtin_amdgcn_global_load_lds((const __attribute__((address_space(1))) void*)(g), \
                                     (__attribute__((address_space(3))) void*)(l), 16, 0, 0)

// log2-domain scale: 1/sqrt(64) * 1/ln(2)
#define QSCALE 0.180336880f

// ---------- ws layout (bytes) ----------
#define WS_WT   0          // 3*64*512*2 = 196608   WT[m][d][c] bf16
#define WS_KBF  196608     // 8*4096*64*2 = 4194304
#define WS_VTB  4390912    // 8*64*4096*2 = 4194304 (per batch: Vt[d][s])
#define WS_OP   8585216    // 8*8192*64*2 = 8388608 (bf16 [split][row][d])
#define WS_ML   16973824   // 8*8192*2*4  = 524288  (f32 [split][row][{m,l}], log2 domain)

// qb (bf16 q*QSCALE, [8192][64]) aliases d_out's out section (written last by combine).

// ---------------- k1: fused prep ----------------
__global__ __launch_bounds__(256) void prep(const float* __restrict__ ck,
                                            const float* __restrict__ cv,
                                            const float* __restrict__ Wq,
                                            const float* __restrict__ Wk,
                                            const float* __restrict__ Wv,
                                            float* __restrict__ kout,
                                            float* __restrict__ vout,
                                            __bf16* __restrict__ kb,
                                            __bf16* __restrict__ vtb,
                                            __bf16* __restrict__ wt) {
    __shared__ __bf16 vl[64][72];              // 9216 B, shared by V and W branches
    const int blk = blockIdx.x;
    const int tid = threadIdx.x;
    if (blk < 768) {
#pragma unroll
        for (int it = 0; it < 2; ++it) {
            const int i = blk * 256 + tid + it * 196608;
            const int b = i / 49152;
            const int f = i - b * 49152;
            const int s = f >> 4, d = (f & 15) * 4;
            const float4 kd = ((const float4*)ck)[i];
            ((float4*)(kout + (size_t)b * TTOT * HD))[f] = kd;
            bf16x4 k4;
            k4[0] = (__bf16)kd.x; k4[1] = (__bf16)kd.y;
            k4[2] = (__bf16)kd.z; k4[3] = (__bf16)kd.w;
            *(bf16x4*)(kb + (size_t)b * TTOT * HD + s * HD + d) = k4;
        }
    } else if (blk < 1152) {
        const int tb = blk - 768;
        const int b = tb / 48, si = tb - (tb / 48) * 48;
        const int sbase = si * 64;
        const float4* src = (const float4*)(cv + ((size_t)b * TCACHE + sbase) * HD);
        float4* dstf = (float4*)(vout + ((size_t)b * TTOT + sbase) * HD);
#pragma unroll
        for (int k = 0; k < 4; ++k) {
            const int f = tid + 256 * k;
            const int s = f >> 4, d4 = (f & 15) * 4;
            const float4 v = src[f];
            dstf[f] = v;
            bf16x4 t;
            t[0] = (__bf16)v.x; t[1] = (__bf16)v.y;
            t[2] = (__bf16)v.z; t[3] = (__bf16)v.w;
            *(bf16x4*)&vl[s][d4] = t;
        }
        __syncthreads();
        const int d = tid >> 2, sc = tid & 3;
        bf16x8 o0, o1;
#pragma unroll
        for (int i = 0; i < 8; ++i) {
            o0[i] = vl[sc * 16 + i][d];
            o1[i] = vl[sc * 16 + 8 + i][d];
        }
        __bf16* vt = vtb + ((size_t)b * HD + d) * TTOT + sbase + sc * 16;
        *(bf16x8*)vt = o0;
        *(bf16x8*)(vt + 8) = o1;
    } else {
        const int tb = blk - 1152;                 // 0..23
        const int m = tb >> 3;
        const int ct = (tb & 7) * 64;
        const float* W = (m == 0) ? Wq : (m == 1) ? Wk : Wv;
        const float4* src = (const float4*)(W + (size_t)ct * HD);
#pragma unroll
        for (int k = 0; k < 4; ++k) {
            const int f = tid + 256 * k;
            const int c = f >> 4, d4 = (f & 15) * 4;
            const float4 v = src[f];
            bf16x4 t;
            t[0] = (__bf16)v.x; t[1] = (__bf16)v.y;
            t[2] = (__bf16)v.z; t[3] = (__bf16)v.w;
            *(bf16x4*)&vl[c][d4] = t;
        }
        __syncthreads();
        const int d = tid >> 2, sc = tid & 3;
        bf16x8 o0, o1;
#pragma unroll
        for (int i = 0; i < 8; ++i) {
            o0[i] = vl[sc * 16 + i][d];
            o1[i] = vl[sc * 16 + 8 + i][d];
        }
        __bf16* wr = wt + (size_t)m * HD * EMB + (size_t)d * EMB + ct + sc * 16;
        *(bf16x8*)wr = o0;
        *(bf16x8*)(wr + 8) = o1;
    }
}

// ---------------- k2: MFMA projections (2 waves/block, 32 rows, grid 256) ----------------
__global__ __launch_bounds__(128) void proj_mfma(const float* __restrict__ x,
                                                 const __bf16* __restrict__ wt,
                                                 __bf16* __restrict__ qb,
                                                 float* __restrict__ kout,
                                                 float* __restrict__ vout,
                                                 __bf16* __restrict__ kb,
                                                 __bf16* __restrict__ vtb) {
    __shared__ __bf16 xs[32][520];                 // 33 KB
    __shared__ __bf16 vls[2][64][24];              // 6 KB
    const int tid = threadIdx.x;
    const int w = tid >> 6, lane = tid & 63;
    const int lo = lane & 15, hi = lane >> 4;
    const int r0 = blockIdx.x * 32 + w * 16;
    const int b = r0 >> 10;
    const int t0r = r0 & (TNEW - 1);

    {   // stage 32x512 f32 -> bf16 LDS (coalesced)
        const float4* xg = (const float4*)(x + (size_t)blockIdx.x * 32 * EMB);
#pragma unroll
        for (int k = 0; k < 32; ++k) {
            const int f = tid + 128 * k;           // 0..4095
            const int row = f >> 7, col4 = (f & 127) * 4;
            const float4 v = xg[f];
            bf16x4 t;
            t[0] = (__bf16)v.x; t[1] = (__bf16)v.y;
            t[2] = (__bf16)v.z; t[3] = (__bf16)v.w;
            *(bf16x4*)&xs[row][col4] = t;
        }
    }
    __syncthreads();

    for (int m = 0; m < 3; ++m) {
        const __bf16* wm = wt + (size_t)m * HD * EMB;
        f32x4 acc[4];
#pragma unroll
        for (int n = 0; n < 4; ++n) acc[n] = (f32x4){0.f, 0.f, 0.f, 0.f};
#pragma unroll
        for (int c = 0; c < 16; ++c) {
            const bf16x8 ax = *(const bf16x8*)&xs[w * 16 + lo][c * 32 + hi * 8];
#pragma unroll
            for (int n = 0; n < 4; ++n) {
                const bf16x8 bw = *(const bf16x8*)(wm + (size_t)(n * 16 + lo) * EMB + c * 32 + hi * 8);
                acc[n] = MFMA(ax, bw, acc[n]);
            }
        }
#pragma unroll
        for (int n = 0; n < 4; ++n) {
#pragma unroll
            for (int rr = 0; rr < 4; ++rr) {
                const int grow = r0 + hi * 4 + rr;
                const int t = grow & (TNEW - 1);
                const int d = n * 16 + lo;
                const float val = acc[n][rr];
                if (m == 0) {
                    qb[(size_t)grow * HD + d] = (__bf16)(val * QSCALE);
                } else if (m == 1) {
                    const size_t kv = ((size_t)b * TTOT + TCACHE + t) * HD + d;
                    kout[kv] = val;
                    kb[kv] = (__bf16)val;
                } else {
                    const size_t kv = ((size_t)b * TTOT + TCACHE + t) * HD + d;
                    vout[kv] = val;
                    vls[w][d][hi * 4 + rr] = (__bf16)val;
                }
            }
        }
    }
    __syncthreads();
    bf16x8 v0 = *(const bf16x8*)&vls[w][lane][0];
    bf16x8 v1 = *(const bf16x8*)&vls[w][lane][8];
    __bf16* vt = vtb + ((size_t)b * HD + lane) * TTOT + TCACHE + t0r;
    *(bf16x8*)vt = v0;
    *(bf16x8*)(vt + 8) = v1;
}

// ---------------- k3: flash attention, LDS-shared K/V, counted-vmcnt 3-buffer pipeline ----------------
// grid 512 = 8 batches x 8 qblocks(128 rows) x 8 cyclic splits; 8 waves x 16 rows.
// T4: loads stay in flight ACROSS the barrier (s_waitcnt vmcnt(2), never 0 mid-loop).
#define QB 128
#define NSPLIT 8
__global__ __launch_bounds__(512, 4) void attn_mfma(const __bf16* __restrict__ qb,
                                                    const __bf16* __restrict__ kb,
                                                    const __bf16* __restrict__ vtb,
                                                    __bf16* __restrict__ Opart,
                                                    float* __restrict__ mlpart) {
    __shared__ __align__(16) __bf16 Kt[3][64 * 64];      // 24 KB
    __shared__ __align__(16) __bf16 Vts[3][64 * 64];     // 24 KB
    __shared__ __align__(16) __bf16 P_lds[8][16][72];    // 18 KB  (66 KB total, 2 blk/CU)

    const int tid = threadIdx.x;
    const int wv = tid >> 6, lane = tid & 63;
    const int lo = lane & 15, hi = lane >> 4;

    const int bid = blockIdx.x;
    const int b = bid & 7;                 // XCD-major
    const int idx = bid >> 3;              // 0..63
    const int split = idx & 7;
    const int qloc = idx >> 3;             // 0..7
    const int t0 = qloc * QB;
    const int row0 = b * TNEW + t0;

    const int ntiles = (TCACHE + t0 + QB) >> 6;          // 50 + 2*qloc
    const int count = (ntiles - split + 7) >> 3;         // 6..7, uniform

    const __bf16* Kb = kb + (size_t)b * TTOT * HD;
    const __bf16* Vb = vtb + (size_t)b * HD * TTOT;

    // staging: wave wv stages rows [wv*8, wv*8+8); source pre-swizzled (rule #21)
    const int r_sub = lane >> 3;                       // 0..7
    const int row_st = wv * 8 + r_sub;
    const int c_st = ((lane & 7) * 16) ^ (r_sub << 4);

#define STAGE(s, bi) do { \
        const char* gk_ = (const char*)Kb + (size_t)((s) + row_st) * 128 + c_st; \
        const char* gv_ = (const char*)Vb + ((size_t)row_st * TTOT + (s)) * 2 + c_st; \
        GLOAD_LDS16(gk_, Kt[bi] + row_st * 64); \
        GLOAD_LDS16(gv_, Vts[bi] + row_st * 64); \
    } while (0)

    // Q: wave owns 16 rows
    const int t0w = t0 + wv * 16;
    const __bf16* Qw = qb + (size_t)(row0 + wv * 16) * HD;
    const bf16x8 aq0 = *(const bf16x8*)(Qw + (size_t)lo * HD + hi * 8);
    const bf16x8 aq1 = *(const bf16x8*)(Qw + (size_t)lo * HD + 32 + hi * 8);

    f32x4 o[4];
    float mg = -1e30f, lg = 0.f;
#pragma unroll
    for (int n = 0; n < 4; ++n) o[n] = (f32x4){0.f, 0.f, 0.f, 0.f};

    // ---- prologue: 2-deep prefetch ----
    STAGE(split * 64, 0);
    if (count > 1) {
        STAGE(split * 64 + 512, 1);
        // vmcnt retires oldest-first: leaves only buf1's 2 loads outstanding,
        // so Q loads + buf0 loads have landed.
        asm volatile("s_waitcnt vmcnt(2)" ::: "memory");
    } else {
        asm volatile("s_waitcnt vmcnt(0)" ::: "memory");
    }
    __builtin_amdgcn_s_barrier();
    __builtin_amdgcn_sched_barrier(0);

    const int sw = (lo & 7) << 3;   // element-level read swizzle

    int s0 = split * 64;
    int buf = 0;
    for (int it = 0; it < count; ++it, s0 += NSPLIT * 64) {
        const __bf16* Kl = Kt[buf];
        const __bf16* Vl = Vts[buf];

        bf16x8 bk[4][2], bv[4][2];
#pragma unroll
        for (int kg = 0; kg < 4; ++kg) {
            const int kr = (kg * 16 + lo) * 64;
            bk[kg][0] = *(const bf16x8*)(Kl + kr + ((hi * 8) ^ sw));
            bk[kg][1] = *(const bf16x8*)(Kl + kr + ((32 + hi * 8) ^ sw));
        }
#pragma unroll
        for (int n = 0; n < 4; ++n) {
            const int vr = (n * 16 + lo) * 64;
            bv[n][0] = *(const bf16x8*)(Vl + vr + ((hi * 8) ^ sw));
            bv[n][1] = *(const bf16x8*)(Vl + vr + ((32 + hi * 8) ^ sw));
        }

        // ---- swapped QK^T: rows=keys, cols=q-rows; lane owns q-row `lo` ----
        const f32x4 z = (f32x4){0.f, 0.f, 0.f, 0.f};
        f32x4 sc[4];
#pragma unroll
        for (int kg = 0; kg < 4; ++kg) {
            sc[kg] = MFMA(bk[kg][0], aq0, z);
            sc[kg] = MFMA(bk[kg][1], aq1, sc[kg]);
        }

        if (s0 + 63 > TCACHE + t0w) {
            const int lim = TCACHE + t0w + lo;   // per-lane q-row limit
#pragma unroll
            for (int kg = 0; kg < 4; ++kg)
#pragma unroll
                for (int rr = 0; rr < 4; ++rr)
                    if (s0 + kg * 16 + hi * 4 + rr > lim) sc[kg][rr] = -1e30f;
        }

        // ---- row max: 15 in-lane + 2 shuffles ----
        f32x4 mx = sc[0];
        mx = (f32x4){fmaxf(mx[0], sc[1][0]), fmaxf(mx[1], sc[1][1]),
                     fmaxf(mx[2], sc[1][2]), fmaxf(mx[3], sc[1][3])};
        mx = (f32x4){fmaxf(mx[0], sc[2][0]), fmaxf(mx[1], sc[2][1]),
                     fmaxf(mx[2], sc[2][2]), fmaxf(mx[3], sc[2][3])};
        mx = (f32x4){fmaxf(mx[0], sc[3][0]), fmaxf(mx[1], sc[3][1]),
                     fmaxf(mx[2], sc[3][2]), fmaxf(mx[3], sc[3][3])};
        float mt = fmaxf(fmaxf(mx[0], mx[1]), fmaxf(mx[2], mx[3]));
        mt = fmaxf(mt, __shfl_xor(mt, 16));
        mt = fmaxf(mt, __shfl_xor(mt, 32));

        if (__any(mt > mg + 8.0f)) {          // defer-max rescale (rare)
            const float mn = fmaxf(mg, mt);
            const float corr = exp2f(mg - mn);
            lg *= corr;
            mg = mn;
            float cb[4];
#pragma unroll
            for (int rr = 0; rr < 4; ++rr) cb[rr] = __shfl(corr, hi * 4 + rr);
#pragma unroll
            for (int n = 0; n < 4; ++n)
#pragma unroll
                for (int rr = 0; rr < 4; ++rr) o[n][rr] *= cb[rr];
        }

        // ---- exp + sum + packed P write (4 x ds_write_b64) ----
        float ps = 0.f;
#pragma unroll
        for (int kg = 0; kg < 4; ++kg) {
            const float e0 = exp2f(sc[kg][0] - mg);
            const float e1 = exp2f(sc[kg][1] - mg);
            const float e2 = exp2f(sc[kg][2] - mg);
            const float e3 = exp2f(sc[kg][3] - mg);
            ps += (e0 + e1) + (e2 + e3);
            bf16x4 pk;
            pk[0] = (__bf16)e0; pk[1] = (__bf16)e1;
            pk[2] = (__bf16)e2; pk[3] = (__bf16)e3;
            *(bf16x4*)&P_lds[wv][lo][kg * 16 + hi * 4] = pk;
        }
        ps += __shfl_xor(ps, 16);
        ps += __shfl_xor(ps, 32);
        lg += ps;
        asm volatile("" ::: "memory");

        // ---- PV: A = P[qrow][key] row-major, B = V frags ----
        const bf16x8 ap0 = *(const bf16x8*)&P_lds[wv][lo][hi * 8];
        const bf16x8 ap1 = *(const bf16x8*)&P_lds[wv][lo][32 + hi * 8];
#pragma unroll
        for (int n = 0; n < 4; ++n) o[n] = MFMA(ap0, bv[n][0], o[n]);
#pragma unroll
        for (int n = 0; n < 4; ++n) o[n] = MFMA(ap1, bv[n][1], o[n]);
        asm volatile("" ::: "memory");

        // ---- issue prefetch for tile it+2 into buf consumed at it-1 (safe: barrier-separated) ----
        if (it + 2 < count) {
            int nb = buf + 2; if (nb >= 3) nb -= 3;
            STAGE(s0 + 2 * NSPLIT * 64, nb);
        }
        // ---- counted wait + barrier: L(it+1) landed, L(it+2) stays in flight ----
        if (it + 1 < count) {
            if (it + 2 < count) { asm volatile("s_waitcnt vmcnt(2)" ::: "memory"); }
            else                { asm volatile("s_waitcnt vmcnt(0)" ::: "memory"); }
            __builtin_amdgcn_s_barrier();
            __builtin_amdgcn_sched_barrier(0);
        }
        buf = (buf == 2) ? 0 : buf + 1;
    }
#undef STAGE

    // ---- write partials ----
    __bf16* Ow = Opart + ((size_t)split * (NB * TNEW) + row0 + wv * 16) * HD;
#pragma unroll
    for (int n = 0; n < 4; ++n)
#pragma unroll
        for (int rr = 0; rr < 4; ++rr)
            Ow[(size_t)(hi * 4 + rr) * HD + n * 16 + lo] = (__bf16)o[n][rr];
    if (hi == 0) {
        float* mlw = mlpart + ((size_t)split * (NB * TNEW) + row0 + wv * 16) * 2;
        mlw[lo * 2]     = mg;
        mlw[lo * 2 + 1] = lg;
    }
}

// ---------------- k4: combine key-split partials ----------------
__global__ __launch_bounds__(256) void combine(const __bf16* __restrict__ Opart,
                                               const float* __restrict__ mlpart,
                                               float* __restrict__ out) {
    const int e = blockIdx.x * 256 + threadIdx.x;
    const int lane = threadIdx.x & 63;
    const int row = e >> 6, d = e & 63;
    const float2 ml2 = *(const float2*)&mlpart[(((size_t)(lane & 7)) * (NB * TNEW) + row) * 2];
    float mf = -1e30f;
#pragma unroll
    for (int s = 0; s < NSPLIT; ++s) mf = fmaxf(mf, __shfl(ml2.x, s));
    float lf = 0.f, acc = 0.f;
#pragma unroll
    for (int s = 0; s < NSPLIT; ++s) {
        const float ms = __shfl(ml2.x, s);
        const float ls = __shfl(ml2.y, s);
        const float f = exp2f(ms - mf);
        lf += ls * f;
        acc += (float)Opart[((size_t)s * (NB * TNEW) + row) * HD + d] * f;
    }
    out[e] = acc / lf;
}

extern "C" void kernel_launch(void* const* d_in, const int* in_sizes, int n_in,
                              void* d_out, int out_size, void* d_ws, size_t ws_size,
                              hipStream_t stream) {
    (void)in_sizes; (void)n_in; (void)out_size; (void)ws_size;
    const float* x  = (const float*)d_in[0];
    const float* ck = (const float*)d_in[2];
    const float* cv = (const float*)d_in[3];
    const float* Wq = (const float*)d_in[4];
    const float* Wk = (const float*)d_in[5];
    const float* Wv = (const float*)d_in[6];

    float* out  = (float*)d_out;
    float* kout = out + (size_t)NB * TNEW * HD;
    float* vout = kout + (size_t)NB * TTOT * HD;

    char* ws = (char*)d_ws;
    __bf16* wt  = (__bf16*)(ws + WS_WT);
    __bf16* kbf = (__bf16*)(ws + WS_KBF);
    __bf16* vtb = (__bf16*)(ws + WS_VTB);
    __bf16* Op  = (__bf16*)(ws + WS_OP);
    float*  ml  = (float*)(ws + WS_ML);
    __bf16* qb  = (__bf16*)d_out;

    prep<<<dim3(1176), dim3(256), 0, stream>>>(ck, cv, Wq, Wk, Wv, kout, vout, kbf, vtb, wt);
    proj_mfma<<<dim3(256), dim3(128), 0, stream>>>(x, wt, qb, kout, vout, kbf, vtb);
    attn_mfma<<<dim3(512), dim3(512), 0, stream>>>(qb, kbf, vtb, Op, ml);
    combine<<<dim3(2048), dim3(256), 0, stream>>>(Op, ml, out);
}